// Round 3
// baseline (50.602 us; speedup 1.0000x reference)
//
#include <hip/hip_runtime.h>

#define F_IN  128
#define HID   16
#define CF_IN 64
#define TN    64   // nodes per tile = wave size
#define KC    32   // k-chunk (floats of the feature dim staged per pass)
#define LSTR  65   // padded node-stride: bank = (k + node) % 32 -> 2-way max (free)

// GCN aggregation is exactly the identity here (row==col after the reference's
// broadcast+reshape), so each conv is x@W + b. Edge_index is never read.
//
// Main kernel: 1 wave per block. Blocks [0, nodeTiles) process 64-node tiles
// (coalesced global->LDS staging, thread-per-node compute, wave-uniform weight
// loads -> s_load). Blocks [nodeTiles, nodeTiles+nWC) process 64 cols each.
// No __syncthreads anywhere; per-wave LDS ops are in-order.

__global__ __launch_bounds__(64) void main_kernel(
    const float* __restrict__ x, const float* __restrict__ xc,
    const float* __restrict__ W1, const float* __restrict__ b1,
    const float* __restrict__ W2, const float* __restrict__ b2,
    const float* __restrict__ Wn, const float* __restrict__ bn,
    const float* __restrict__ Wc1, const float* __restrict__ bc1,
    const float* __restrict__ Wc2, const float* __restrict__ bc2,
    float* __restrict__ pN, float* __restrict__ pC,
    int totalN, int N, int B, int C, int nodeTiles, int nWC)
{
    const int lane = threadIdx.x;
    const int bx = blockIdx.x;
    __shared__ float lds[KC * LSTR];   // 8320 B -> ~19 blocks/CU by LDS

    float val;      // per-lane scalar result (node or col)
    int myb;        // batch this lane's element belongs to
    int nW, widx;   // partial-array geometry for the write
    float* pOut;

    if (bx < nodeTiles) {
        // ---------------- node path: 64-node tile ----------------
        const int tileBase = bx * TN;
        const int sub = lane >> 3;   // node sub-index within an 8-row group
        const int k4l = lane & 7;    // float4 column within the 32-float chunk

        float acc[HID];
#pragma unroll
        for (int j = 0; j < HID; j++) acc[j] = b1[j];   // uniform -> s_load

        for (int kc = 0; kc < F_IN / KC; ++kc) {
            // stage chunk: 64 rows x 32 floats, transposed into LDS[k][node]
            float4 v[8];
#pragma unroll
            for (int i = 0; i < 8; ++i) {
                int ng = tileBase + i * 8 + sub;
                if (ng > totalN - 1) ng = totalN - 1;          // clamp (tail)
                v[i] = *reinterpret_cast<const float4*>(
                    x + (size_t)ng * F_IN + kc * KC + k4l * 4);
            }
#pragma unroll
            for (int i = 0; i < 8; ++i) {
                const int node = i * 8 + sub;
                const int kb = k4l * 4;
                lds[(kb + 0) * LSTR + node] = v[i].x;
                lds[(kb + 1) * LSTR + node] = v[i].y;
                lds[(kb + 2) * LSTR + node] = v[i].z;
                lds[(kb + 3) * LSTR + node] = v[i].w;
            }
            // compute: lane = node, all weight indices wave-uniform
#pragma unroll
            for (int k = 0; k < KC; ++k) {
                const float xs = lds[k * LSTR + lane];
                const float4* wv =
                    reinterpret_cast<const float4*>(W1 + (kc * KC + k) * HID);
                const float4 w0 = wv[0], w1 = wv[1], w2 = wv[2], w3 = wv[3];
                acc[0]  = fmaf(xs, w0.x, acc[0]);
                acc[1]  = fmaf(xs, w0.y, acc[1]);
                acc[2]  = fmaf(xs, w0.z, acc[2]);
                acc[3]  = fmaf(xs, w0.w, acc[3]);
                acc[4]  = fmaf(xs, w1.x, acc[4]);
                acc[5]  = fmaf(xs, w1.y, acc[5]);
                acc[6]  = fmaf(xs, w1.z, acc[6]);
                acc[7]  = fmaf(xs, w1.w, acc[7]);
                acc[8]  = fmaf(xs, w2.x, acc[8]);
                acc[9]  = fmaf(xs, w2.y, acc[9]);
                acc[10] = fmaf(xs, w2.z, acc[10]);
                acc[11] = fmaf(xs, w2.w, acc[11]);
                acc[12] = fmaf(xs, w3.x, acc[12]);
                acc[13] = fmaf(xs, w3.y, acc[13]);
                acc[14] = fmaf(xs, w3.z, acc[14]);
                acc[15] = fmaf(xs, w3.w, acc[15]);
            }
        }

        // layer 2 (16x16) + relu, layer 3 (16->1); all weights uniform
        float h1[HID];
#pragma unroll
        for (int j = 0; j < HID; j++) h1[j] = fmaxf(acc[j], 0.f);
        float h2[HID];
#pragma unroll
        for (int j = 0; j < HID; j++) h2[j] = b2[j];
#pragma unroll
        for (int kk = 0; kk < HID; kk++) {
            const float* wr = W2 + kk * HID;
#pragma unroll
            for (int j = 0; j < HID; j++) h2[j] = fmaf(h1[kk], wr[j], h2[j]);
        }
        float o = bn[0];
#pragma unroll
        for (int kk = 0; kk < HID; kk++) o = fmaf(fmaxf(h2[kk], 0.f), Wn[kk], o);

        const int ng = tileBase + lane;
        val = (ng < totalN) ? o : 0.f;
        myb = ng / N;          // magic-mul division, once per tile
        nW = nodeTiles; widx = bx; pOut = pN;
    } else {
        // ---------------- col path: 64 cols per wave ----------------
        const int cw = bx - nodeTiles;
        const int cg = cw * TN + lane;
        const int totC = B * C;
        const int cc = (cg < totC) ? cg : totC - 1;
        const float* __restrict__ row = xc + (size_t)cc * CF_IN;

        float acc[HID];
#pragma unroll
        for (int j = 0; j < HID; j++) acc[j] = bc1[j];
#pragma unroll
        for (int k4 = 0; k4 < CF_IN / 4; ++k4) {
            const float4 xv = reinterpret_cast<const float4*>(row)[k4];
#pragma unroll
            for (int r = 0; r < 4; ++r) {
                const float xs = (r == 0) ? xv.x : (r == 1) ? xv.y
                               : (r == 2) ? xv.z : xv.w;
                const float* wr = Wc1 + (k4 * 4 + r) * HID;   // uniform
#pragma unroll
                for (int j = 0; j < HID; j++) acc[j] = fmaf(xs, wr[j], acc[j]);
            }
        }
        float o = bc2[0];
#pragma unroll
        for (int kk = 0; kk < HID; kk++) o = fmaf(fmaxf(acc[kk], 0.f), Wc2[kk], o);

        val = (cg < totC) ? o : 0.f;
        myb = cg / C;
        nW = nWC; widx = cw; pOut = pC;
    }

    // per-batch masked wave reduction; every (b, wave) slot written -> no init needed
    for (int b = 0; b < B; ++b) {
        float s = (myb == b) ? val : 0.f;
#pragma unroll
        for (int off = 32; off > 0; off >>= 1) s += __shfl_down(s, off, 64);
        if (lane == 0) pOut[(size_t)b * nW + widx] = s;
    }
}

__global__ __launch_bounds__(256) void finish_kernel(
    const float* __restrict__ pN, const float* __restrict__ pC,
    const float* __restrict__ Wf, const float* __restrict__ bf,
    const float* __restrict__ Wo, const float* __restrict__ bo,
    float* __restrict__ out, int nWN, int nWC, int N, int C, int B)
{
    const int t = threadIdx.x;
    const int wave = t >> 6, lane = t & 63;
    __shared__ float s[16];   // B <= 8

    for (int p = wave; p < 2 * B; p += 4) {
        const int b = p >> 1, kind = p & 1;
        float v = 0.f;
        if (kind == 0) {
            for (int i = lane; i < nWN; i += 64) v += pN[(size_t)b * nWN + i];
        } else {
            for (int i = lane; i < nWC; i += 64) v += pC[(size_t)b * nWC + i];
        }
#pragma unroll
        for (int off = 32; off > 0; off >>= 1) v += __shfl_down(v, off, 64);
        if (lane == 0) s[p] = v;
    }
    __syncthreads();

    if (t == 0) {
        for (int b = 0; b < B; ++b) {
            const float navg = s[2 * b + 0] / (float)N;
            const float cavg = s[2 * b + 1] / (float)C;
            float o = bo[0];
#pragma unroll
            for (int j = 0; j < HID; j++) {
                const float h = fmaf(navg, Wf[j], fmaf(cavg, Wf[HID + j], bf[j]));
                o = fmaf(fmaxf(h, 0.f), Wo[j], o);
            }
            out[b] = o;
        }
    }
}

extern "C" void kernel_launch(void* const* d_in, const int* in_sizes, int n_in,
                              void* d_out, int out_size, void* d_ws, size_t ws_size,
                              hipStream_t stream) {
    const float* x   = (const float*)d_in[0];
    const float* xc  = (const float*)d_in[1];
    // d_in[2] = edge_index: unused (row==col degeneracy -> GCN aggregation is identity)
    const float* W1  = (const float*)d_in[3];
    const float* b1  = (const float*)d_in[4];
    const float* W2  = (const float*)d_in[5];
    const float* b2  = (const float*)d_in[6];
    const float* Wn  = (const float*)d_in[7];
    const float* bn  = (const float*)d_in[8];
    const float* Wc1 = (const float*)d_in[9];
    const float* bc1 = (const float*)d_in[10];
    const float* Wc2 = (const float*)d_in[11];
    const float* bc2 = (const float*)d_in[12];
    const float* Wf  = (const float*)d_in[13];
    const float* bf  = (const float*)d_in[14];
    const float* Wo  = (const float*)d_in[15];
    const float* bo  = (const float*)d_in[16];

    const int C = 1000;
    const int B = in_sizes[1] / (C * CF_IN);     // col_features [B, 1000, 64]
    const int N = in_sizes[0] / (B * F_IN);      // node_features [B, N, 128]
    const int totalN = B * N;

    const int nodeTiles = (totalN + TN - 1) / TN;       // 3125
    const int nWC = (B * C + TN - 1) / TN;              // 32

    float* pN = (float*)d_ws;                    // [B][nodeTiles], always overwritten
    float* pC = pN + (size_t)B * nodeTiles;      // [B][nWC]

    main_kernel<<<nodeTiles + nWC, TN, 0, stream>>>(
        x, xc, W1, b1, W2, b2, Wn, bn, Wc1, bc1, Wc2, bc2,
        pN, pC, totalN, N, B, C, nodeTiles, nWC);
    finish_kernel<<<1, 256, 0, stream>>>(pN, pC, Wf, bf, Wo, bo, (float*)d_out,
                                         nodeTiles, nWC, N, C, B);
}